// Round 3
// baseline (108.851 us; speedup 1.0000x reference)
//
#include <hip/hip_runtime.h>

// Fused: conv3x3(6ch, VALID) + relu + shifted-product edge logic + 2x2 mean pool.
// x: (1,1,2048,2048) f32, w: (6,1,3,3) f32
// out: concat[ mult_x (12,2046,2046) f32 , pooled (12,1023,1023) f32 ]
//
// Design (R3): no LDS staging (5x5 window is L1-resident), 64x4 blocks so each
// wave stores 512B contiguous per instruction, channel-pair conv to cut live
// registers, predicated clamp fixups instead of a cloned edge path, and
// nontemporal stores for the streaming output.

static constexpr int XD = 2048;   // input dim
static constexpr int HF = 2046;   // conv-valid output dim
static constexpr int HP = 1023;   // pooled dim
static constexpr float THR = 0.01f;

typedef float v2f __attribute__((ext_vector_type(2)));

// conv+relu for channels CHA,CHB over the 3x3 site patch, from the 5x5 window.
// cR/cC: site row/col 2 is out of range (global 2046) -> replace by row/col 1
// (i.e. the clamped "last row maps to itself" semantics of shift0/shift1).
template<int CHA, int CHB>
__device__ __forceinline__ void conv_pair(const float (&win)[5][5],
                                          const float* __restrict__ w,
                                          bool cR, bool cC,
                                          float (&fA)[3][3], float (&fB)[3][3]) {
#pragma unroll
    for (int pr = 0; pr < 3; ++pr)
#pragma unroll
        for (int pc = 0; pc < 3; ++pc) {
            float a = 0.f, b = 0.f;
#pragma unroll
            for (int ki = 0; ki < 3; ++ki)
#pragma unroll
                for (int kj = 0; kj < 3; ++kj) {
                    const float xv = win[pr + ki][pc + kj];
                    a = fmaf(xv, w[CHA * 9 + ki * 3 + kj], a);
                    b = fmaf(xv, w[CHB * 9 + ki * 3 + kj], b);
                }
            fA[pr][pc] = fmaxf(a, 0.f);
            fB[pr][pc] = fmaxf(b, 0.f);
        }
#pragma unroll
    for (int q = 0; q < 3; ++q) {
        fA[2][q] = cR ? fA[1][q] : fA[2][q];
        fB[2][q] = cR ? fB[1][q] : fB[2][q];
    }
#pragma unroll
    for (int p = 0; p < 3; ++p) {
        fA[p][2] = cC ? fA[p][1] : fA[p][2];
        fB[p][2] = cC ? fB[p][1] : fB[p][2];
    }
}

// One branch (V,H channel pair) -> outputs KB..KB+5 for the 2x2 quad.
template<int CHV, int CHH, int KB>
__device__ __forceinline__ void branch_eval(
    const float (&win)[5][5], const float* __restrict__ w,
    const float (&m_fd)[2][2], const float (&m_sd)[2][2],
    const float (&m_fdd)[2][2], const float (&m_sdd)[2][2],
    bool cR, bool cC, bool inb, int fr0, int fc0, int qx, int qy,
    float* __restrict__ mult, float* __restrict__ pooled)
{
    float fV[3][3], fH[3][3];
    conv_pair<CHV, CHH>(win, w, cR, cC, fV, fH);

    float pl[6] = {0.f, 0.f, 0.f, 0.f, 0.f, 0.f};
#pragma unroll
    for (int py = 0; py < 2; ++py) {
        float o2[6][2];
#pragma unroll
        for (int px = 0; px < 2; ++px) {
            const bool z0 = (py == 0) && cR;   // shift0 zero-row (r == HF-2)
            const bool z1 = (px == 0) && cC;   // shift1 zero-col (c == HF-2)
            const float v = fV[py][px], h = fH[py][px];
            const float vs0  = z0 ? 0.f : fV[py + 1][px];
            const float hs0  = z0 ? 0.f : fH[py + 1][px];
            const float vs1  = z1 ? 0.f : fV[py][px + 1];
            const float hs1  = z1 ? 0.f : fH[py][px + 1];
            const float vs01 = (z0 || z1) ? 0.f : fV[py + 1][px + 1];
            const float hs01 = (z0 || z1) ? 0.f : fH[py + 1][px + 1];
            const float vert  = vs0 * v;
            const float horiz = hs1 * h;
            o2[0][px] = (vert  <= THR) ? horiz : 0.f;
            o2[1][px] = vs01 * v * m_fd[py][px];
            o2[2][px] = (horiz <= THR) ? vert  : 0.f;
            o2[3][px] = vs0 * vs1 * m_sd[py][px];
            o2[4][px] = hs01 * h * m_fdd[py][px];
            o2[5][px] = hs0 * hs1 * m_sdd[py][px];
        }
        if (inb) {
            float* mrow = mult + (size_t)(fr0 + py) * HF + fc0;
#pragma unroll
            for (int k = 0; k < 6; ++k) {
                v2f val; val[0] = o2[k][0]; val[1] = o2[k][1];
                __builtin_nontemporal_store(
                    val, reinterpret_cast<v2f*>(mrow + (size_t)(KB + k) * HF * HF));
            }
        }
#pragma unroll
        for (int k = 0; k < 6; ++k) pl[k] += o2[k][0] + o2[k][1];
    }
    if (inb) {
#pragma unroll
        for (int k = 0; k < 6; ++k)
            __builtin_nontemporal_store(
                0.25f * pl[k],
                pooled + (size_t)(KB + k) * HP * HP + (size_t)qy * HP + qx);
    }
}

__global__ __launch_bounds__(256) void first_level_fused(
    const float* __restrict__ x,
    const float* __restrict__ w,
    float* __restrict__ out)
{
    const int tx = threadIdx.x;              // 0..63 (one wave per ty)
    const int ty = threadIdx.y;              // 0..3
    const int qx = blockIdx.x * 64 + tx;     // pooled coords
    const int qy = blockIdx.y * 4 + ty;
    const int fr0 = 2 * qy, fc0 = 2 * qx;    // top-left pixel of the quad
    const bool cR  = (fr0 == HF - 2);        // site row 2 invalid -> clamp
    const bool cC  = (fc0 == HF - 2);
    const bool inb = (qx < HP) && (qy < HP);

    // 5x5 input window, straight from global (L1-resident tile).
    float win[5][5];
    if (fr0 + 4 <= XD - 1 && fc0 + 4 <= XD - 1) {
        const float* p0 = x + (size_t)fr0 * XD + fc0;
#pragma unroll
        for (int i = 0; i < 5; ++i) {
            const float* pr = p0 + (size_t)i * XD;
            v2f a = *reinterpret_cast<const v2f*>(pr);
            v2f b = *reinterpret_cast<const v2f*>(pr + 2);
            win[i][0] = a[0]; win[i][1] = a[1];
            win[i][2] = b[0]; win[i][3] = b[1];
            win[i][4] = pr[4];
        }
    } else {
        int ri[5], ci[5];
#pragma unroll
        for (int t = 0; t < 5; ++t) {
            ri[t] = min(fr0 + t, XD - 1);
            ci[t] = min(fc0 + t, XD - 1);
        }
#pragma unroll
        for (int i = 0; i < 5; ++i)
#pragma unroll
            for (int j = 0; j < 5; ++j)
                win[i][j] = x[(size_t)ri[i] * XD + ci[j]];
    }

    // masks from D1 (ch4), D2 (ch5)
    float m_fd[2][2], m_sd[2][2], m_fdd[2][2], m_sdd[2][2];
    {
        float d1[3][3], d2[3][3];
        conv_pair<4, 5>(win, w, cR, cC, d1, d2);
#pragma unroll
        for (int py = 0; py < 2; ++py)
#pragma unroll
            for (int px = 0; px < 2; ++px) {
                const bool z0 = (py == 0) && cR;
                const bool z1 = (px == 0) && cC;
                const float a1 = d1[py][px], a2 = d2[py][px];
                const float s1_1 = z1 ? 0.f : d1[py][px + 1];
                const float s1_2 = z1 ? 0.f : d2[py][px + 1];
                const float s0_1 = z0 ? 0.f : d1[py + 1][px];
                const float s0_2 = z0 ? 0.f : d2[py + 1][px];
                m_fd [py][px] = (a1 * s1_1 <= THR) ? 1.f : 0.f;
                m_sd [py][px] = (a2 * s1_2 <= THR) ? 1.f : 0.f;
                m_fdd[py][px] = (a1 * s0_1 <= THR) ? 1.f : 0.f;
                m_sdd[py][px] = (a2 * s0_2 <= THR) ? 1.f : 0.f;
            }
    }

    float* __restrict__ mult   = out;
    float* __restrict__ pooled = out + (size_t)12 * HF * HF;

    // branch a: V1=ch0, H1=ch2 -> k0..5 ; branch b: oV1=ch1, oH1=ch3 -> k6..11
    branch_eval<0, 2, 0>(win, w, m_fd, m_sd, m_fdd, m_sdd,
                         cR, cC, inb, fr0, fc0, qx, qy, mult, pooled);
    branch_eval<1, 3, 6>(win, w, m_fd, m_sd, m_fdd, m_sdd,
                         cR, cC, inb, fr0, fc0, qx, qy, mult, pooled);
}

extern "C" void kernel_launch(void* const* d_in, const int* in_sizes, int n_in,
                              void* d_out, int out_size, void* d_ws, size_t ws_size,
                              hipStream_t stream) {
    const float* x = (const float*)d_in[0];
    const float* w = (const float*)d_in[1];
    float* out = (float*)d_out;
    (void)in_sizes; (void)n_in; (void)out_size; (void)d_ws; (void)ws_size;

    dim3 block(64, 4);
    dim3 grid(16, 256);   // 16*64 = 1024 quads in x, 256*4 = 1024 in y
    hipLaunchKernelGGL(first_level_fused, grid, block, 0, stream, x, w, out);
}

// Round 4
// 52.427 us; speedup vs baseline: 2.0762x; 2.0762x over previous
//
#include <hip/hip_runtime.h>

// Fused: conv3x3(6ch, VALID) + relu + shifted-product edge logic + 2x2 mean pool.
// x: (1,1,2048,2048) f32, w: (6,1,3,3) f32
// out: concat[ mult_x (12,2046,2046) f32 , pooled (12,1023,1023) f32 ]
//
// R4: back to LDS staging (R2 base, 74us). New: 64x4 blocks, each thread owns
// a 4-wide x 2-high pixel strip -> mult stores are 1KB contiguous per wave
// (dwordx4/lane), pooled stores float2. Channel-pair conv streaming (each
// channel computed exactly once), bit-packed suppression masks, conflict-free
// ds_read_b128 fragment reads. No nontemporal stores.

static constexpr int XD = 2048;   // input dim
static constexpr int HF = 2046;   // conv-valid output dim
static constexpr int HP = 1023;   // pooled dim
static constexpr float THR = 0.01f;

typedef float v4f __attribute__((ext_vector_type(4), aligned(4)));
typedef float v2f __attribute__((ext_vector_type(2), aligned(4)));

// conv+relu for channels CA,CB over the 3x5 site patch from the 5x8 window.
// cR: site row 2 (global fr+2==2046) invalid -> copy site row 1 (self-clamp).
// cC: site cols 2..4 (global >=2046) invalid -> copy site col 1.
template<int CA, int CB>
__device__ __forceinline__ void conv_pair(const float (&win)[5][8],
                                          const float* __restrict__ w,
                                          bool cR, bool cC,
                                          float (&fA)[3][5], float (&fB)[3][5])
{
#pragma unroll
    for (int sr = 0; sr < 3; ++sr)
#pragma unroll
        for (int sc = 0; sc < 5; ++sc) {
            float a = 0.f, b = 0.f;
#pragma unroll
            for (int ki = 0; ki < 3; ++ki)
#pragma unroll
                for (int kj = 0; kj < 3; ++kj) {
                    const float xv = win[sr + ki][sc + kj];
                    a = fmaf(xv, w[CA * 9 + ki * 3 + kj], a);
                    b = fmaf(xv, w[CB * 9 + ki * 3 + kj], b);
                }
            fA[sr][sc] = fmaxf(a, 0.f);
            fB[sr][sc] = fmaxf(b, 0.f);
        }
    // row fixup first, then col (corner thread gets both -> fA[2][>=2]=fA[1][1])
#pragma unroll
    for (int sc = 0; sc < 5; ++sc) {
        fA[2][sc] = cR ? fA[1][sc] : fA[2][sc];
        fB[2][sc] = cR ? fB[1][sc] : fB[2][sc];
    }
#pragma unroll
    for (int sr = 0; sr < 3; ++sr)
#pragma unroll
        for (int sc = 2; sc < 5; ++sc) {
            fA[sr][sc] = cC ? fA[sr][1] : fA[sr][sc];
            fB[sr][sc] = cC ? fB[sr][1] : fB[sr][sc];
        }
}

// One branch (V,H channel pair) -> planes KB..KB+5 for the 2x4 strip.
template<int CV, int CH, int KB>
__device__ __forceinline__ void branch_eval(
    const float (&win)[5][8], const float* __restrict__ w, unsigned mb,
    bool cR, bool cC, bool rowsValid, int fr, int fc0, int qy, int pc0,
    float* __restrict__ mult, float* __restrict__ pooled)
{
    float fV[3][5], fH[3][5];
    conv_pair<CV, CH>(win, w, cR, cC, fV, fH);

    float pl[6][2];
#pragma unroll
    for (int k = 0; k < 6; ++k) { pl[k][0] = 0.f; pl[k][1] = 0.f; }

#pragma unroll
    for (int py = 0; py < 2; ++py) {
        float o[6][4];
#pragma unroll
        for (int px = 0; px < 4; ++px) {
            const bool z0 = cR && (py == 0);   // r == HF-2: shift0 row -> 0
            const bool z1 = cC && (px == 0);   // c == HF-2: shift1 col -> 0
            const float v = fV[py][px], h = fH[py][px];
            const float vs0  = z0 ? 0.f : fV[py + 1][px];
            const float hs0  = z0 ? 0.f : fH[py + 1][px];
            const float vs1  = z1 ? 0.f : fV[py][px + 1];
            const float hs1  = z1 ? 0.f : fH[py][px + 1];
            const float vs01 = (z0 || z1) ? 0.f : fV[py + 1][px + 1];
            const float hs01 = (z0 || z1) ? 0.f : fH[py + 1][px + 1];
            const float vert  = vs0 * v;
            const float horiz = hs1 * h;
            const int base = py * 4 + px;
            o[0][px] = (vert  <= THR) ? horiz : 0.f;
            o[1][px] = ((mb >> base)        & 1u) ? vs01 * v   : 0.f;
            o[2][px] = (horiz <= THR) ? vert  : 0.f;
            o[3][px] = ((mb >> (8  + base)) & 1u) ? vs0 * vs1  : 0.f;
            o[4][px] = ((mb >> (16 + base)) & 1u) ? hs01 * h   : 0.f;
            o[5][px] = ((mb >> (24 + base)) & 1u) ? hs0 * hs1  : 0.f;
        }
        if (rowsValid) {
            float* mrow = mult + (size_t)(fr + py) * HF + fc0;
            if (cC) {   // only cols 2044,2045 exist
#pragma unroll
                for (int k = 0; k < 6; ++k) {
                    v2f val; val[0] = o[k][0]; val[1] = o[k][1];
                    *reinterpret_cast<v2f*>(mrow + (size_t)(KB + k) * HF * HF) = val;
                }
            } else {
#pragma unroll
                for (int k = 0; k < 6; ++k) {
                    v4f val;
                    val[0] = o[k][0]; val[1] = o[k][1];
                    val[2] = o[k][2]; val[3] = o[k][3];
                    *reinterpret_cast<v4f*>(mrow + (size_t)(KB + k) * HF * HF) = val;
                }
            }
        }
#pragma unroll
        for (int k = 0; k < 6; ++k) {
            pl[k][0] += o[k][0] + o[k][1];
            pl[k][1] += o[k][2] + o[k][3];
        }
    }
    if (rowsValid) {
#pragma unroll
        for (int k = 0; k < 6; ++k) {
            float* pp = pooled + (size_t)(KB + k) * HP * HP + (size_t)qy * HP + pc0;
            if (cC) {
                *pp = 0.25f * pl[k][0];   // second pool cell (1023) is OOB
            } else {
                v2f val; val[0] = 0.25f * pl[k][0]; val[1] = 0.25f * pl[k][1];
                *reinterpret_cast<v2f*>(pp) = val;
            }
        }
    }
}

__global__ __launch_bounds__(256) void first_level_fused(
    const float* __restrict__ x,
    const float* __restrict__ w,
    float* __restrict__ out)
{
    // Block tile: output rows [R0, R0+8) (2 per ty), cols [C0, C0+256) (4 per tx).
    // Conv sites needed: rows R0..R0+8, cols C0..C0+256 (incl. shift halo).
    // Input needed: rows R0..R0+10 (11), cols C0..C0+258 (259) -> LDS [11][260].
    __shared__ float xs[11][260];

    const int tx = threadIdx.x;            // 0..63 (one wave per ty)
    const int ty = threadIdx.y;            // 0..3
    const int tid = ty * 64 + tx;
    const int R0 = blockIdx.y * 8;
    const int C0 = blockIdx.x * 256;

#pragma unroll
    for (int it = 0; it < 12; ++it) {
        const int idx = tid + it * 256;
        if (idx < 11 * 259) {
            const int lr = idx / 259;
            const int lc = idx - lr * 259;
            const int gr = min(R0 + lr, XD - 1);
            const int gc = min(C0 + lc, XD - 1);
            xs[lr][lc] = x[gr * XD + gc];
        }
    }
    __syncthreads();

    const int fr  = R0 + 2 * ty;           // first output row of this thread
    const int fc0 = C0 + 4 * tx;           // first output col
    const int qy  = fr >> 1;               // pooled row
    const int pc0 = fc0 >> 1;              // first pooled col
    const bool rowsValid = (fr < HF);      // fr+1 < HF too (fr even)
    const bool cR = (fr  == HF - 2);       // site row 2 == 2046 -> clamp
    const bool cC = (fc0 == HF - 2);       // site cols >= 2046 -> clamp

    // 5x8 input window from LDS: rows 2ty..2ty+4, cols 4tx..4tx+7
    // (two ds_read_b128 per row, 16B lane stride -> conflict-free)
    float win[5][8];
#pragma unroll
    for (int i = 0; i < 5; ++i) {
        const v4f a = *reinterpret_cast<const v4f*>(&xs[2 * ty + i][4 * tx]);
        const v4f b = *reinterpret_cast<const v4f*>(&xs[2 * ty + i][4 * tx + 4]);
        win[i][0] = a[0]; win[i][1] = a[1]; win[i][2] = a[2]; win[i][3] = a[3];
        win[i][4] = b[0]; win[i][5] = b[1]; win[i][6] = b[2]; win[i][7] = b[3];
    }

    // Suppression masks from D1 (ch4), D2 (ch5), bit-packed:
    // bit layout: m*8 + py*4 + px for m in {fd, sd, fdd, sdd}
    unsigned mb = 0;
    {
        float d1[3][5], d2[3][5];
        conv_pair<4, 5>(win, w, cR, cC, d1, d2);
#pragma unroll
        for (int py = 0; py < 2; ++py)
#pragma unroll
            for (int px = 0; px < 4; ++px) {
                const bool z0 = cR && (py == 0);
                const bool z1 = cC && (px == 0);
                const float a1 = d1[py][px], a2 = d2[py][px];
                const float s11 = z1 ? 0.f : d1[py][px + 1];
                const float s12 = z1 ? 0.f : d2[py][px + 1];
                const float s01 = z0 ? 0.f : d1[py + 1][px];
                const float s02 = z0 ? 0.f : d2[py + 1][px];
                const int base = py * 4 + px;
                mb |= (a1 * s11 <= THR ? 1u : 0u) << base;
                mb |= (a2 * s12 <= THR ? 1u : 0u) << (8 + base);
                mb |= (a1 * s01 <= THR ? 1u : 0u) << (16 + base);
                mb |= (a2 * s02 <= THR ? 1u : 0u) << (24 + base);
            }
    }

    float* __restrict__ mult   = out;
    float* __restrict__ pooled = out + (size_t)12 * HF * HF;

    // branch a: V1=ch0, H1=ch2 -> planes 0..5; branch b: oV1=ch1, oH1=ch3 -> 6..11
    branch_eval<0, 2, 0>(win, w, mb, cR, cC, rowsValid, fr, fc0, qy, pc0,
                         mult, pooled);
    branch_eval<1, 3, 6>(win, w, mb, cR, cC, rowsValid, fr, fc0, qy, pc0,
                         mult, pooled);
}

extern "C" void kernel_launch(void* const* d_in, const int* in_sizes, int n_in,
                              void* d_out, int out_size, void* d_ws, size_t ws_size,
                              hipStream_t stream) {
    const float* x = (const float*)d_in[0];
    const float* w = (const float*)d_in[1];
    float* out = (float*)d_out;
    (void)in_sizes; (void)n_in; (void)out_size; (void)d_ws; (void)ws_size;

    dim3 block(64, 4);
    dim3 grid(8, 256);   // x: 8*256=2048 cols >= 2046 ; y: 256*8=2048 rows >= 2046
    hipLaunchKernelGGL(first_level_fused, grid, block, 0, stream, x, w, out);
}